// Round 4
// baseline (205.345 us; speedup 1.0000x reference)
//
#include <hip/hip_runtime.h>
#include <hip/hip_bf16.h>
#include <math.h>

#define S_LEN 2048
#define BATCH 4
#define HDIM 768
#define LOUT 9
#define NROWS (BATCH*S_LEN)
#define K2H 1536
#define WIN 11
#define NEG_INF_F (-1e30f)

typedef __attribute__((ext_vector_type(4))) float f32x4;
typedef __attribute__((ext_vector_type(8))) short bf16x8;

static __device__ __forceinline__ void async_ld16(const void* g, void* l) {
  __builtin_amdgcn_global_load_lds((const __attribute__((address_space(1))) void*)g,
                                   (__attribute__((address_space(3))) void*)l, 16, 0, 0);
}

static __device__ __forceinline__ unsigned short f2bf(float f) {
  union { float f; unsigned int u; } v; v.f = f;
  unsigned int u = v.u;
  unsigned int r = (u + 0x7fffu + ((u >> 16) & 1u)) >> 16;
  return (unsigned short)r;
}

// Kernel 1: W1 [1536][768] fp32 -> W1t [768][1536] bf16 (LDS-tiled transpose)
__global__ __launch_bounds__(256) void k_prep_w1t(const float* __restrict__ W1,
                                                  unsigned short* __restrict__ W1t) {
  __shared__ float tile[32][33];
  int bk = blockIdx.x % 48;   // k-tile (1536/32)
  int bn = blockIdx.x / 48;   // n-tile (768/32)
  int tc = threadIdx.x % 32;
  int tr = threadIdx.x / 32;  // 0..7
  #pragma unroll
  for (int i = 0; i < 32; i += 8) {
    tile[tr + i][tc] = W1[(bk*32 + tr + i) * HDIM + bn*32 + tc];
  }
  __syncthreads();
  #pragma unroll
  for (int i = 0; i < 32; i += 8) {
    W1t[(bn*32 + tr + i) * K2H + bk*32 + tc] = f2bf(tile[tc][tr + i]);
  }
}

// Kernel 2 (fully fused): per row —
//   scores for the 11 window rows (from x in regs), window softmax,
//   weighted ctx -> xc[768:1536] bf16, x center -> xc[0:768] bf16,
//   base logits = x·Wc + bc.
__global__ __launch_bounds__(256) void k_ctx(const float* __restrict__ x,
                                             const float* __restrict__ wa,
                                             const float* __restrict__ ba,
                                             const float* __restrict__ Wc,
                                             const float* __restrict__ bc,
                                             unsigned short* __restrict__ xc,
                                             float* __restrict__ base) {
  __shared__ float sred[4][WIN];
  __shared__ float redp[4][LOUT];
  int row = blockIdx.x;
  int b = row >> 11, s = row & 2047;
  int t = threadIdx.x;
  int lane = t & 63, wave = t >> 6;

  // load 11 window rows (3 elems each) into registers
  float xv[WIN][3];
  bool vld[WIN];
  #pragma unroll
  for (int w = 0; w < WIN; ++w) {
    int j = s - 5 + w;
    bool valid = (j >= 0) && (j < S_LEN);
    vld[w] = valid;
    int jc = valid ? j : (j < 0 ? 0 : S_LEN - 1);
    const float* xr = x + (b * S_LEN + jc) * HDIM;
    xv[w][0] = xr[t];
    xv[w][1] = xr[t + 256];
    xv[w][2] = xr[t + 512];
  }
  float wa0 = wa[t], wa1 = wa[t + 256], wa2 = wa[t + 512];

  // 11 dot-product partials, wave reduce, cross-wave reduce
  float sp[WIN];
  #pragma unroll
  for (int w = 0; w < WIN; ++w)
    sp[w] = xv[w][0] * wa0 + xv[w][1] * wa1 + xv[w][2] * wa2;
  #pragma unroll
  for (int w = 0; w < WIN; ++w)
    #pragma unroll
    for (int m = 1; m < 64; m <<= 1) sp[w] += __shfl_xor(sp[w], m);
  if (lane == 0) {
    #pragma unroll
    for (int w = 0; w < WIN; ++w) sred[wave][w] = sp[w];
  }
  __syncthreads();
  float bav = ba[0];
  float sc[WIN];
  #pragma unroll
  for (int w = 0; w < WIN; ++w) {
    float v = sred[0][w] + sred[1][w] + sred[2][w] + sred[3][w] + bav;
    sc[w] = vld[w] ? v : NEG_INF_F;
  }
  // softmax over 11 (every thread redundantly)
  float mx = sc[0];
  #pragma unroll
  for (int w = 1; w < WIN; ++w) mx = fmaxf(mx, sc[w]);
  float es[WIN], ssum = 0.f;
  #pragma unroll
  for (int w = 0; w < WIN; ++w) {
    es[w] = vld[w] ? __expf(sc[w] - mx) : 0.f;
    ssum += es[w];
  }
  float inv = 1.f / ssum;

  // weighted ctx
  float c0 = 0.f, c1 = 0.f, c2 = 0.f;
  #pragma unroll
  for (int w = 0; w < WIN; ++w) {
    float aw = es[w] * inv;
    c0 += aw * xv[w][0];
    c1 += aw * xv[w][1];
    c2 += aw * xv[w][2];
  }
  unsigned short* dstc = xc + row * K2H;
  // first half: x center (w=5 is always the valid row s)
  dstc[t]       = f2bf(xv[5][0]);
  dstc[t + 256] = f2bf(xv[5][1]);
  dstc[t + 512] = f2bf(xv[5][2]);
  // second half: ctx
  dstc[HDIM + t]       = f2bf(c0);
  dstc[HDIM + t + 256] = f2bf(c1);
  dstc[HDIM + t + 512] = f2bf(c2);

  // base logits from center row
  float p[LOUT] = {};
  #pragma unroll
  for (int i = 0; i < 3; ++i) {
    int e = t + i * 256;
    float xvv = xv[5][i];
    const float* wrow = Wc + e * LOUT;
    #pragma unroll
    for (int l = 0; l < LOUT; ++l) p[l] += xvv * wrow[l];
  }
  #pragma unroll
  for (int l = 0; l < LOUT; ++l)
    #pragma unroll
    for (int m = 1; m < 64; m <<= 1) p[l] += __shfl_xor(p[l], m);
  if (lane == 0) {
    #pragma unroll
    for (int l = 0; l < LOUT; ++l) redp[wave][l] = p[l];
  }
  __syncthreads();
  if (t < LOUT) {
    base[row * LOUT + t] = redp[0][t] + redp[1][t] + redp[2][t] + redp[3][t] + bc[t];
  }
}

// Kernel 3: h = xc(bf16,[8192][1536]) @ W1t^T + b1 -> fp32 [8192][768]
// 128x64 tile, BK=32, double-buffered (24 KB LDS -> 4 blocks/CU),
// prefetch-before-compute, both-sides XOR slot swizzle (2-way conflicts = free).
__global__ __launch_bounds__(256, 4) void k_gemm(const unsigned short* __restrict__ A,
                                                 const unsigned short* __restrict__ Bt,
                                                 const float* __restrict__ b1,
                                                 float* __restrict__ Hout) {
  __shared__ unsigned short As[2][128 * 32];  // 8 KB x2
  __shared__ unsigned short Bs[2][64 * 32];   // 4 KB x2
  int bid = blockIdx.x;
  int obid = (bid & 7) * 96 + (bid >> 3);     // XCD swizzle (768%8==0, bijective)
  int bm = obid / 12, bn = obid % 12;
  int t = threadIdx.x;
  int lane = t & 63, wave = t >> 6;

  // --- staging: lane covers row (l>>2), slot (l&3) of a 16-row chunk ---
  // swizzle: phys slot p of row r holds global slot p ^ f(r), f(r)=(r^(r>>2))&3.
  // For staging rows, r&3=(l>>2)&3 and (r>>2)&3=(l>>4)&3 (chunk bases are %16==0):
  int fl = ((lane >> 2) ^ (lane >> 4)) & 3;
  int sSrc = ((lane & 3) ^ fl);               // global slot this lane fetches
  int rIn = lane >> 2;                        // row within 16-row chunk

  const unsigned short* gA = A  + (bm * 128 + wave * 32 + rIn) * K2H + sSrc * 8;
  const unsigned short* gB = Bt + (bn * 64  + wave * 16 + rIn) * K2H + sSrc * 8;

  f32x4 acc[2][4] = {};

  // --- read side ---
  int laneRow = lane & 15;
  int slot = lane >> 4;                       // 0..3 (8 elems each)
  int fr = ((lane & 3) ^ ((lane >> 2) & 3));  // f(laneRow): row bases are %16==0
  int rdOff = ((slot ^ fr) & 3) * 8;          // swizzled element offset within row

#define STAGE(buf, kt) do {                                                    \
    async_ld16(gA + (kt),             &As[buf][(wave * 32) * 32]);             \
    async_ld16(gA + 16 * K2H + (kt),  &As[buf][(wave * 32 + 16) * 32]);        \
    async_ld16(gB + (kt),             &Bs[buf][(wave * 16) * 32]);             \
  } while (0)

#define COMPUTE(buf) do {                                                      \
    bf16x8 af[2], bfv[4];                                                      \
    _Pragma("unroll")                                                          \
    for (int m = 0; m < 2; ++m)                                                \
      af[m] = *(const bf16x8*)(&As[buf][(wave * 32 + m * 16 + laneRow) * 32 + rdOff]); \
    _Pragma("unroll")                                                          \
    for (int n = 0; n < 4; ++n)                                                \
      bfv[n] = *(const bf16x8*)(&Bs[buf][(n * 16 + laneRow) * 32 + rdOff]);    \
    _Pragma("unroll")                                                          \
    for (int m = 0; m < 2; ++m)                                                \
      _Pragma("unroll")                                                        \
      for (int n = 0; n < 4; ++n)                                              \
        acc[m][n] = __builtin_amdgcn_mfma_f32_16x16x32_bf16(af[m], bfv[n], acc[m][n], 0, 0, 0); \
  } while (0)

  STAGE(0, 0);
  __syncthreads();
  int cur = 0;
  for (int kt = 32; kt < K2H; kt += 32) {
    STAGE(cur ^ 1, kt);          // prefetch next K-tile; stays in flight over MFMA
    COMPUTE(cur);
    __syncthreads();
    cur ^= 1;
  }
  COMPUTE(cur);

  int orow = bm * 128 + wave * 32 + (lane >> 4) * 4;
  int ocol = bn * 64 + (lane & 15);
  #pragma unroll
  for (int m = 0; m < 2; ++m)
    #pragma unroll
    for (int n = 0; n < 4; ++n) {
      int col = ocol + n * 16;
      float bv = b1[col];
      #pragma unroll
      for (int r = 0; r < 4; ++r) {
        Hout[(orow + m * 16 + r) * HDIM + col] = acc[m][n][r] + bv;
      }
    }
#undef STAGE
#undef COMPUTE
}

// Kernel 4: LayerNorm + exact GELU + W2 matvec (9) + 0.5/0.5 combine with base
__global__ __launch_bounds__(256) void k_ln(const float* __restrict__ Hin,
                                            const float* __restrict__ gamma,
                                            const float* __restrict__ beta,
                                            const float* __restrict__ W2,
                                            const float* __restrict__ b2,
                                            const float* __restrict__ base,
                                            float* __restrict__ out) {
  __shared__ float redS[4], redQ[4], redp[4][LOUT];
  int row = blockIdx.x;
  int t = threadIdx.x;
  int lane = t & 63, wave = t >> 6;
  const float* hr = Hin + row * HDIM;
  float v0 = hr[t], v1 = hr[t + 256], v2 = hr[t + 512];
  float s1 = v0 + v1 + v2;
  float s2 = v0 * v0 + v1 * v1 + v2 * v2;
  #pragma unroll
  for (int m = 1; m < 64; m <<= 1) { s1 += __shfl_xor(s1, m); s2 += __shfl_xor(s2, m); }
  if (lane == 0) { redS[wave] = s1; redQ[wave] = s2; }
  __syncthreads();
  s1 = redS[0] + redS[1] + redS[2] + redS[3];
  s2 = redQ[0] + redQ[1] + redQ[2] + redQ[3];
  float mu = s1 * (1.f / HDIM);
  float var = s2 * (1.f / HDIM) - mu * mu;
  float rstd = rsqrtf(var + 1e-5f);
  float p[LOUT] = {};
  float vv[3] = { v0, v1, v2 };
  #pragma unroll
  for (int i = 0; i < 3; ++i) {
    int e = t + i * 256;
    float g = (vv[i] - mu) * rstd * gamma[e] + beta[e];
    float gg = 0.5f * g * (1.f + erff(g * 0.70710678118654752f));
    const float* wrow = W2 + e * LOUT;
    #pragma unroll
    for (int l = 0; l < LOUT; ++l) p[l] += gg * wrow[l];
  }
  #pragma unroll
  for (int l = 0; l < LOUT; ++l)
    #pragma unroll
    for (int m = 1; m < 64; m <<= 1) p[l] += __shfl_xor(p[l], m);
  if (lane == 0) {
    #pragma unroll
    for (int l = 0; l < LOUT; ++l) redp[wave][l] = p[l];
  }
  __syncthreads();
  if (t < LOUT) {
    float cl = redp[0][t] + redp[1][t] + redp[2][t] + redp[3][t] + b2[t];
    out[row * LOUT + t] = 0.5f * base[row * LOUT + t] + 0.5f * cl;
  }
}

extern "C" void kernel_launch(void* const* d_in, const int* in_sizes, int n_in,
                              void* d_out, int out_size, void* d_ws, size_t ws_size,
                              hipStream_t stream) {
  const float* x     = (const float*)d_in[0];
  const float* Wc    = (const float*)d_in[1];
  const float* bc    = (const float*)d_in[2];
  const float* wa    = (const float*)d_in[3];
  const float* ba    = (const float*)d_in[4];
  const float* W1    = (const float*)d_in[5];
  const float* b1    = (const float*)d_in[6];
  const float* gamma = (const float*)d_in[7];
  const float* beta  = (const float*)d_in[8];
  const float* W2    = (const float*)d_in[9];
  const float* b2    = (const float*)d_in[10];
  float* out = (float*)d_out;

  char* ws = (char*)d_ws;
  unsigned short* xc  = (unsigned short*)(ws);             // 8192*1536*2  = 25,165,824
  unsigned short* w1t = (unsigned short*)(ws + 25165824);  // 768*1536*2   =  2,359,296
  float* base         = (float*)(ws + 27525120);           // 8192*9*4     =    294,912
  float* hbuf         = (float*)(ws + 27820032);           // 8192*768*4   = 25,165,824

  k_prep_w1t<<<dim3(1152), dim3(256), 0, stream>>>(W1, w1t);
  k_ctx     <<<dim3(8192), dim3(256), 0, stream>>>(x, wa, ba, Wc, bc, xc, base);
  k_gemm    <<<dim3(768),  dim3(256), 0, stream>>>(xc, w1t, b1, hbuf);
  k_ln      <<<dim3(8192), dim3(256), 0, stream>>>(hbuf, gamma, beta, W2, b2, base, out);
}

// Round 5
// 183.480 us; speedup vs baseline: 1.1192x; 1.1192x over previous
//
#include <hip/hip_runtime.h>
#include <hip/hip_bf16.h>
#include <math.h>

#define S_LEN 2048
#define BATCH 4
#define HDIM 768
#define LOUT 9
#define NROWS (BATCH*S_LEN)
#define K2H 1536
#define WIN 11
#define NEG_INF_F (-1e30f)

typedef __attribute__((ext_vector_type(4))) float f32x4;
typedef __attribute__((ext_vector_type(8))) short bf16x8;

static __device__ __forceinline__ void async_ld16(const void* g, void* l) {
  __builtin_amdgcn_global_load_lds((const __attribute__((address_space(1))) void*)g,
                                   (__attribute__((address_space(3))) void*)l, 16, 0, 0);
}

static __device__ __forceinline__ unsigned short f2bf(float f) {
  union { float f; unsigned int u; } v; v.f = f;
  unsigned int u = v.u;
  unsigned int r = (u + 0x7fffu + ((u >> 16) & 1u)) >> 16;
  return (unsigned short)r;
}

static __device__ __forceinline__ float bf2f(unsigned short h) {
  union { unsigned int u; float f; } v; v.u = ((unsigned int)h) << 16;
  return v.f;
}

// Kernel 1: W1 [1536][768] fp32 -> W1t [768][1536] bf16 (LDS-tiled transpose)
__global__ __launch_bounds__(256) void k_prep_w1t(const float* __restrict__ W1,
                                                  unsigned short* __restrict__ W1t) {
  __shared__ float tile[32][33];
  int bk = blockIdx.x % 48;
  int bn = blockIdx.x / 48;
  int tc = threadIdx.x % 32;
  int tr = threadIdx.x / 32;
  #pragma unroll
  for (int i = 0; i < 32; i += 8) {
    tile[tr + i][tc] = W1[(bk*32 + tr + i) * HDIM + bn*32 + tc];
  }
  __syncthreads();
  #pragma unroll
  for (int i = 0; i < 32; i += 8) {
    W1t[(bn*32 + tr + i) * K2H + bk*32 + tc] = f2bf(tile[tc][tr + i]);
  }
}

// Kernel 2: one pass over fp32 x per row —
//   x -> bf16 first half of xc, score = x·wa+ba (once), base logits = x·Wc+bc.
// 192 threads (3 waves), thread owns 4 contiguous elements.
// XCD swizzle: each XCD gets a contiguous 1024-row range.
__global__ __launch_bounds__(192) void k_prep(const float* __restrict__ x,
                                              const float* __restrict__ wa,
                                              const float* __restrict__ ba,
                                              const float* __restrict__ Wc,
                                              const float* __restrict__ bc,
                                              unsigned short* __restrict__ xc,
                                              float* __restrict__ scores,
                                              float* __restrict__ base) {
  __shared__ float red[3][LOUT + 1];
  int bid = blockIdx.x;
  int row = (bid & 7) * 1024 + (bid >> 3);
  int t = threadIdx.x;
  int lane = t & 63, wave = t >> 6;
  const float4 v = *(const float4*)(x + row * HDIM + t * 4);
  const float4 w = *(const float4*)(wa + t * 4);
  ushort4 o;
  o.x = f2bf(v.x); o.y = f2bf(v.y); o.z = f2bf(v.z); o.w = f2bf(v.w);
  *(ushort4*)(xc + row * K2H + t * 4) = o;

  float pv[LOUT + 1];
  pv[LOUT] = v.x * w.x + v.y * w.y + v.z * w.z + v.w * w.w;   // score partial
  #pragma unroll
  for (int l = 0; l < LOUT; ++l) pv[l] = 0.f;
  const float xvv[4] = { v.x, v.y, v.z, v.w };
  #pragma unroll
  for (int j = 0; j < 4; ++j) {
    const float* wr = Wc + (t * 4 + j) * LOUT;
    #pragma unroll
    for (int l = 0; l < LOUT; ++l) pv[l] += xvv[j] * wr[l];
  }
  #pragma unroll
  for (int l = 0; l <= LOUT; ++l)
    #pragma unroll
    for (int m = 1; m < 64; m <<= 1) pv[l] += __shfl_xor(pv[l], m);
  if (lane == 0) {
    #pragma unroll
    for (int l = 0; l <= LOUT; ++l) red[wave][l] = pv[l];
  }
  __syncthreads();
  if (t < LOUT) {
    base[row * LOUT + t] = red[0][t] + red[1][t] + red[2][t] + bc[t];
  } else if (t == LOUT) {
    scores[row] = red[0][LOUT] + red[1][LOUT] + red[2][LOUT] + ba[0];
  }
}

// Kernel 3: window softmax (scores precomputed) + weighted ctx from bf16 xc
//   -> bf16 second half of xc. Same XCD swizzle as k_prep (window rows L2-hot).
__global__ __launch_bounds__(192) void k_ctx(const float* __restrict__ scores,
                                             unsigned short* __restrict__ xc) {
  __shared__ float swin[WIN];
  int bid = blockIdx.x;
  int row = (bid & 7) * 1024 + (bid >> 3);
  int b = row >> 11, s = row & 2047;
  int t = threadIdx.x;
  if (t < WIN) {
    int j = s - 5 + t;
    bool valid = (j >= 0) && (j < S_LEN);
    int jc = valid ? j : (j < 0 ? 0 : S_LEN - 1);
    swin[t] = valid ? scores[b * S_LEN + jc] : NEG_INF_F;
  }
  __syncthreads();
  float mx = swin[0];
  #pragma unroll
  for (int w = 1; w < WIN; ++w) mx = fmaxf(mx, swin[w]);
  float es[WIN], ssum = 0.f;
  #pragma unroll
  for (int w = 0; w < WIN; ++w) {
    float sv = swin[w];
    es[w] = (sv > -1e29f) ? __expf(sv - mx) : 0.f;
    ssum += es[w];
  }
  float inv = 1.f / ssum;
  float c0 = 0.f, c1 = 0.f, c2 = 0.f, c3 = 0.f;
  #pragma unroll
  for (int w = 0; w < WIN; ++w) {
    float aw = es[w] * inv;
    int j = s - 5 + w;
    int jc = (j < 0) ? 0 : ((j >= S_LEN) ? S_LEN - 1 : j);
    const ushort4 uv = *(const ushort4*)(xc + (((long)b * S_LEN + jc) * K2H) + t * 4);
    c0 += aw * bf2f(uv.x);
    c1 += aw * bf2f(uv.y);
    c2 += aw * bf2f(uv.z);
    c3 += aw * bf2f(uv.w);
  }
  ushort4 o;
  o.x = f2bf(c0); o.y = f2bf(c1); o.z = f2bf(c2); o.w = f2bf(c3);
  *(ushort4*)(xc + row * K2H + HDIM + t * 4) = o;
}

// Kernel 4: h = xc(bf16,[8192][1536]) @ W1t^T + b1 -> fp32 [8192][768]
// 128x64 tile, BK=32, double-buffered (24 KB LDS -> 4 blocks/CU),
// prefetch-before-compute, both-sides XOR slot swizzle.
__global__ __launch_bounds__(256, 4) void k_gemm(const unsigned short* __restrict__ A,
                                                 const unsigned short* __restrict__ Bt,
                                                 const float* __restrict__ b1,
                                                 float* __restrict__ Hout) {
  __shared__ unsigned short As[2][128 * 32];
  __shared__ unsigned short Bs[2][64 * 32];
  int bid = blockIdx.x;
  int obid = (bid & 7) * 96 + (bid >> 3);
  int bm = obid / 12, bn = obid % 12;
  int t = threadIdx.x;
  int lane = t & 63, wave = t >> 6;

  int fl = ((lane >> 2) ^ (lane >> 4)) & 3;
  int sSrc = ((lane & 3) ^ fl);
  int rIn = lane >> 2;

  const unsigned short* gA = A  + (bm * 128 + wave * 32 + rIn) * K2H + sSrc * 8;
  const unsigned short* gB = Bt + (bn * 64  + wave * 16 + rIn) * K2H + sSrc * 8;

  f32x4 acc[2][4] = {};

  int laneRow = lane & 15;
  int slot = lane >> 4;
  int fr = ((lane & 3) ^ ((lane >> 2) & 3));
  int rdOff = ((slot ^ fr) & 3) * 8;

#define STAGE(buf, kt) do {                                                    \
    async_ld16(gA + (kt),             &As[buf][(wave * 32) * 32]);             \
    async_ld16(gA + 16 * K2H + (kt),  &As[buf][(wave * 32 + 16) * 32]);        \
    async_ld16(gB + (kt),             &Bs[buf][(wave * 16) * 32]);             \
  } while (0)

#define COMPUTE(buf) do {                                                      \
    bf16x8 af[2], bfv[4];                                                      \
    _Pragma("unroll")                                                          \
    for (int m = 0; m < 2; ++m)                                                \
      af[m] = *(const bf16x8*)(&As[buf][(wave * 32 + m * 16 + laneRow) * 32 + rdOff]); \
    _Pragma("unroll")                                                          \
    for (int n = 0; n < 4; ++n)                                                \
      bfv[n] = *(const bf16x8*)(&Bs[buf][(n * 16 + laneRow) * 32 + rdOff]);    \
    _Pragma("unroll")                                                          \
    for (int m = 0; m < 2; ++m)                                                \
      _Pragma("unroll")                                                        \
      for (int n = 0; n < 4; ++n)                                              \
        acc[m][n] = __builtin_amdgcn_mfma_f32_16x16x32_bf16(af[m], bfv[n], acc[m][n], 0, 0, 0); \
  } while (0)

  STAGE(0, 0);
  __syncthreads();
  int cur = 0;
  for (int kt = 32; kt < K2H; kt += 32) {
    STAGE(cur ^ 1, kt);
    COMPUTE(cur);
    __syncthreads();
    cur ^= 1;
  }
  COMPUTE(cur);

  int orow = bm * 128 + wave * 32 + (lane >> 4) * 4;
  int ocol = bn * 64 + (lane & 15);
  #pragma unroll
  for (int m = 0; m < 2; ++m)
    #pragma unroll
    for (int n = 0; n < 4; ++n) {
      int col = ocol + n * 16;
      float bv = b1[col];
      #pragma unroll
      for (int r = 0; r < 4; ++r) {
        Hout[(orow + m * 16 + r) * HDIM + col] = acc[m][n][r] + bv;
      }
    }
#undef STAGE
#undef COMPUTE
}

// Kernel 5: LayerNorm + exact GELU + W2 matvec (9) + 0.5/0.5 combine with base
__global__ __launch_bounds__(256) void k_ln(const float* __restrict__ Hin,
                                            const float* __restrict__ gamma,
                                            const float* __restrict__ beta,
                                            const float* __restrict__ W2,
                                            const float* __restrict__ b2,
                                            const float* __restrict__ base,
                                            float* __restrict__ out) {
  __shared__ float redS[4], redQ[4], redp[4][LOUT];
  int row = blockIdx.x;
  int t = threadIdx.x;
  int lane = t & 63, wave = t >> 6;
  const float* hr = Hin + row * HDIM;
  float v0 = hr[t], v1 = hr[t + 256], v2 = hr[t + 512];
  float s1 = v0 + v1 + v2;
  float s2 = v0 * v0 + v1 * v1 + v2 * v2;
  #pragma unroll
  for (int m = 1; m < 64; m <<= 1) { s1 += __shfl_xor(s1, m); s2 += __shfl_xor(s2, m); }
  if (lane == 0) { redS[wave] = s1; redQ[wave] = s2; }
  __syncthreads();
  s1 = redS[0] + redS[1] + redS[2] + redS[3];
  s2 = redQ[0] + redQ[1] + redQ[2] + redQ[3];
  float mu = s1 * (1.f / HDIM);
  float var = s2 * (1.f / HDIM) - mu * mu;
  float rstd = rsqrtf(var + 1e-5f);
  float p[LOUT] = {};
  float vv[3] = { v0, v1, v2 };
  #pragma unroll
  for (int i = 0; i < 3; ++i) {
    int e = t + i * 256;
    float g = (vv[i] - mu) * rstd * gamma[e] + beta[e];
    float gg = 0.5f * g * (1.f + erff(g * 0.70710678118654752f));
    const float* wrow = W2 + e * LOUT;
    #pragma unroll
    for (int l = 0; l < LOUT; ++l) p[l] += gg * wrow[l];
  }
  #pragma unroll
  for (int l = 0; l < LOUT; ++l)
    #pragma unroll
    for (int m = 1; m < 64; m <<= 1) p[l] += __shfl_xor(p[l], m);
  if (lane == 0) {
    #pragma unroll
    for (int l = 0; l < LOUT; ++l) redp[wave][l] = p[l];
  }
  __syncthreads();
  if (t < LOUT) {
    float cl = redp[0][t] + redp[1][t] + redp[2][t] + redp[3][t] + b2[t];
    out[row * LOUT + t] = 0.5f * base[row * LOUT + t] + 0.5f * cl;
  }
}

extern "C" void kernel_launch(void* const* d_in, const int* in_sizes, int n_in,
                              void* d_out, int out_size, void* d_ws, size_t ws_size,
                              hipStream_t stream) {
  const float* x     = (const float*)d_in[0];
  const float* Wc    = (const float*)d_in[1];
  const float* bc    = (const float*)d_in[2];
  const float* wa    = (const float*)d_in[3];
  const float* ba    = (const float*)d_in[4];
  const float* W1    = (const float*)d_in[5];
  const float* b1    = (const float*)d_in[6];
  const float* gamma = (const float*)d_in[7];
  const float* beta  = (const float*)d_in[8];
  const float* W2    = (const float*)d_in[9];
  const float* b2    = (const float*)d_in[10];
  float* out = (float*)d_out;

  char* ws = (char*)d_ws;
  unsigned short* xc  = (unsigned short*)(ws);             // 8192*1536*2  = 25,165,824
  unsigned short* w1t = (unsigned short*)(ws + 25165824);  // 768*1536*2   =  2,359,296
  float* scores       = (float*)(ws + 27525120);           // 8192*4       =     32,768
  float* base         = (float*)(ws + 27557888);           // 8192*9*4     =    294,912
  float* hbuf         = (float*)(ws + 27852800);           // 8192*768*4   = 25,165,824

  k_prep_w1t<<<dim3(1152), dim3(256), 0, stream>>>(W1, w1t);
  k_prep    <<<dim3(8192), dim3(192), 0, stream>>>(x, wa, ba, Wc, bc, xc, scores, base);
  k_ctx     <<<dim3(8192), dim3(192), 0, stream>>>(scores, xc);
  k_gemm    <<<dim3(768),  dim3(256), 0, stream>>>(xc, w1t, b1, hbuf);
  k_ln      <<<dim3(8192), dim3(256), 0, stream>>>(hbuf, gamma, beta, W2, b2, base, out);
}

// Round 6
// 179.240 us; speedup vs baseline: 1.1456x; 1.0237x over previous
//
#include <hip/hip_runtime.h>
#include <hip/hip_bf16.h>
#include <math.h>

#define S_LEN 2048
#define BATCH 4
#define HDIM 768
#define LOUT 9
#define NROWS (BATCH*S_LEN)
#define K2H 1536
#define WIN 11
#define NEG_INF_F (-1e30f)

typedef __attribute__((ext_vector_type(4))) float f32x4;
typedef __attribute__((ext_vector_type(8))) short bf16x8;

static __device__ __forceinline__ void async_ld16(const void* g, void* l) {
  __builtin_amdgcn_global_load_lds((const __attribute__((address_space(1))) void*)g,
                                   (__attribute__((address_space(3))) void*)l, 16, 0, 0);
}

static __device__ __forceinline__ unsigned short f2bf(float f) {
  union { float f; unsigned int u; } v; v.f = f;
  unsigned int u = v.u;
  unsigned int r = (u + 0x7fffu + ((u >> 16) & 1u)) >> 16;
  return (unsigned short)r;
}

static __device__ __forceinline__ float bf2f(unsigned short h) {
  union { unsigned int u; float f; } v; v.u = ((unsigned int)h) << 16;
  return v.f;
}

// Kernel 1: W1 [1536][768] fp32 -> W1t [768][1536] bf16 (LDS-tiled transpose)
__global__ __launch_bounds__(256) void k_prep_w1t(const float* __restrict__ W1,
                                                  unsigned short* __restrict__ W1t) {
  __shared__ float tile[32][33];
  int bk = blockIdx.x % 48;
  int bn = blockIdx.x / 48;
  int tc = threadIdx.x % 32;
  int tr = threadIdx.x / 32;
  #pragma unroll
  for (int i = 0; i < 32; i += 8) {
    tile[tr + i][tc] = W1[(bk*32 + tr + i) * HDIM + bn*32 + tc];
  }
  __syncthreads();
  #pragma unroll
  for (int i = 0; i < 32; i += 8) {
    W1t[(bn*32 + tr + i) * K2H + bk*32 + tc] = f2bf(tile[tc][tr + i]);
  }
}

// Kernel 2: one pass over fp32 x per row —
//   x -> bf16 first half of xc, score = x·wa+ba (once), base logits = x·Wc+bc.
__global__ __launch_bounds__(192) void k_prep(const float* __restrict__ x,
                                              const float* __restrict__ wa,
                                              const float* __restrict__ ba,
                                              const float* __restrict__ Wc,
                                              const float* __restrict__ bc,
                                              unsigned short* __restrict__ xc,
                                              float* __restrict__ scores,
                                              float* __restrict__ base) {
  __shared__ float red[3][LOUT + 1];
  int bid = blockIdx.x;
  int row = (bid & 7) * 1024 + (bid >> 3);
  int t = threadIdx.x;
  int lane = t & 63, wave = t >> 6;
  const float4 v = *(const float4*)(x + row * HDIM + t * 4);
  const float4 w = *(const float4*)(wa + t * 4);
  ushort4 o;
  o.x = f2bf(v.x); o.y = f2bf(v.y); o.z = f2bf(v.z); o.w = f2bf(v.w);
  *(ushort4*)(xc + row * K2H + t * 4) = o;

  float pv[LOUT + 1];
  pv[LOUT] = v.x * w.x + v.y * w.y + v.z * w.z + v.w * w.w;
  #pragma unroll
  for (int l = 0; l < LOUT; ++l) pv[l] = 0.f;
  const float xvv[4] = { v.x, v.y, v.z, v.w };
  #pragma unroll
  for (int j = 0; j < 4; ++j) {
    const float* wr = Wc + (t * 4 + j) * LOUT;
    #pragma unroll
    for (int l = 0; l < LOUT; ++l) pv[l] += xvv[j] * wr[l];
  }
  #pragma unroll
  for (int l = 0; l <= LOUT; ++l)
    #pragma unroll
    for (int m = 1; m < 64; m <<= 1) pv[l] += __shfl_xor(pv[l], m);
  if (lane == 0) {
    #pragma unroll
    for (int l = 0; l <= LOUT; ++l) red[wave][l] = pv[l];
  }
  __syncthreads();
  if (t < LOUT) {
    base[row * LOUT + t] = red[0][t] + red[1][t] + red[2][t] + bc[t];
  } else if (t == LOUT) {
    scores[row] = red[0][LOUT] + red[1][LOUT] + red[2][LOUT] + ba[0];
  }
}

// Kernel 3: window softmax (scores precomputed) + weighted ctx from bf16 xc
__global__ __launch_bounds__(192) void k_ctx(const float* __restrict__ scores,
                                             unsigned short* __restrict__ xc) {
  __shared__ float swin[WIN];
  int bid = blockIdx.x;
  int row = (bid & 7) * 1024 + (bid >> 3);
  int b = row >> 11, s = row & 2047;
  int t = threadIdx.x;
  if (t < WIN) {
    int j = s - 5 + t;
    bool valid = (j >= 0) && (j < S_LEN);
    int jc = valid ? j : (j < 0 ? 0 : S_LEN - 1);
    swin[t] = valid ? scores[b * S_LEN + jc] : NEG_INF_F;
  }
  __syncthreads();
  float mx = swin[0];
  #pragma unroll
  for (int w = 1; w < WIN; ++w) mx = fmaxf(mx, swin[w]);
  float es[WIN], ssum = 0.f;
  #pragma unroll
  for (int w = 0; w < WIN; ++w) {
    float sv = swin[w];
    es[w] = (sv > -1e29f) ? __expf(sv - mx) : 0.f;
    ssum += es[w];
  }
  float inv = 1.f / ssum;
  float c0 = 0.f, c1 = 0.f, c2 = 0.f, c3 = 0.f;
  #pragma unroll
  for (int w = 0; w < WIN; ++w) {
    float aw = es[w] * inv;
    int j = s - 5 + w;
    int jc = (j < 0) ? 0 : ((j >= S_LEN) ? S_LEN - 1 : j);
    const ushort4 uv = *(const ushort4*)(xc + (((long)b * S_LEN + jc) * K2H) + t * 4);
    c0 += aw * bf2f(uv.x);
    c1 += aw * bf2f(uv.y);
    c2 += aw * bf2f(uv.z);
    c3 += aw * bf2f(uv.w);
  }
  ushort4 o;
  o.x = f2bf(c0); o.y = f2bf(c1); o.z = f2bf(c2); o.w = f2bf(c3);
  *(ushort4*)(xc + row * K2H + HDIM + t * 4) = o;
}

// Kernel 4: h = xc(bf16,[8192][1536]) @ W1t^T + b1 -> fp32 [8192][768]
// 128x64 tile, BK=32, ring-4 LDS buffers, depth-3 prefetch with COUNTED vmcnt
// (never drains to 0 in main loop); one s_barrier per K-step; T5 setprio.
__global__ __launch_bounds__(256, 3) void k_gemm(const unsigned short* __restrict__ A,
                                                 const unsigned short* __restrict__ Bt,
                                                 const float* __restrict__ b1,
                                                 float* __restrict__ Hout) {
  __shared__ unsigned short As[4][128 * 32];  // 8 KB x4
  __shared__ unsigned short Bs[4][64 * 32];   // 4 KB x4  -> 48 KB total
  int bid = blockIdx.x;
  int obid = (bid & 7) * 96 + (bid >> 3);     // XCD swizzle (768%8==0, bijective)
  int bm = obid / 12, bn = obid % 12;
  int t = threadIdx.x;
  int lane = t & 63, wave = t >> 6;

  // staging: lane covers row (l>>2), 16B slot (l&3) of a 16-row chunk;
  // source slot pre-swizzled so linear LDS dest ends up XOR-swizzled (rule #21)
  int fl = ((lane >> 2) ^ (lane >> 4)) & 3;
  int sSrc = ((lane & 3) ^ fl);
  int rIn = lane >> 2;

  const unsigned short* gA = A  + (bm * 128 + wave * 32 + rIn) * K2H + sSrc * 8;
  const unsigned short* gB = Bt + (bn * 64  + wave * 16 + rIn) * K2H + sSrc * 8;

  f32x4 acc[2][4] = {};

  int laneRow = lane & 15;
  int slot = lane >> 4;
  int fr = ((lane & 3) ^ ((lane >> 2) & 3));
  int rdOff = ((slot ^ fr) & 3) * 8;          // swizzled read offset within row

#define STAGE(buf, kt) do {                                                    \
    async_ld16(gA + (kt),             &As[buf][(wave * 32) * 32]);             \
    async_ld16(gA + 16 * K2H + (kt),  &As[buf][(wave * 32 + 16) * 32]);        \
    async_ld16(gB + (kt),             &Bs[buf][(wave * 16) * 32]);             \
  } while (0)

#define COMPUTE(buf) do {                                                      \
    bf16x8 af[2], bfv[4];                                                      \
    _Pragma("unroll")                                                          \
    for (int m = 0; m < 2; ++m)                                                \
      af[m] = *(const bf16x8*)(&As[buf][(wave * 32 + m * 16 + laneRow) * 32 + rdOff]); \
    _Pragma("unroll")                                                          \
    for (int n = 0; n < 4; ++n)                                                \
      bfv[n] = *(const bf16x8*)(&Bs[buf][(n * 16 + laneRow) * 32 + rdOff]);    \
    __builtin_amdgcn_s_setprio(1);                                             \
    _Pragma("unroll")                                                          \
    for (int m = 0; m < 2; ++m)                                                \
      _Pragma("unroll")                                                        \
      for (int n = 0; n < 4; ++n)                                              \
        acc[m][n] = __builtin_amdgcn_mfma_f32_16x16x32_bf16(af[m], bfv[n], acc[m][n], 0, 0, 0); \
    __builtin_amdgcn_s_setprio(0);                                             \
  } while (0)

// counted wait + barrier in one asm; memory clobber pins ordering
#define WBAR(n) asm volatile("s_waitcnt vmcnt(" #n ")\n\ts_barrier" ::: "memory")

  // prologue: stage tiles 0,1,2  (9 loads/thread in flight)
  STAGE(0, 0);
  STAGE(1, 32);
  STAGE(2, 64);

  // main loop: tiles 0..44 (stages 3..47); keep 6 loads (2 tiles) in flight
  for (int tt = 0; tt < 45; ++tt) {
    WBAR(6);                       // tile tt landed; tiles tt+1,tt+2 in flight
    STAGE((tt + 3) & 3, (tt + 3) * 32);
    COMPUTE(tt & 3);
  }
  // tail: tiles 45,46,47 — no more stages
  WBAR(6);  COMPUTE(1);            // tile 45 (45&3==1)
  WBAR(3);  COMPUTE(2);            // tile 46
  WBAR(0);  COMPUTE(3);            // tile 47

  int orow = bm * 128 + wave * 32 + (lane >> 4) * 4;
  int ocol = bn * 64 + (lane & 15);
  #pragma unroll
  for (int m = 0; m < 2; ++m)
    #pragma unroll
    for (int n = 0; n < 4; ++n) {
      int col = ocol + n * 16;
      float bv = b1[col];
      #pragma unroll
      for (int r = 0; r < 4; ++r) {
        Hout[(orow + m * 16 + r) * HDIM + col] = acc[m][n][r] + bv;
      }
    }
#undef STAGE
#undef COMPUTE
#undef WBAR
}

// Kernel 5: LayerNorm + exact GELU + W2 matvec (9) + 0.5/0.5 combine with base
// 192 threads, float4 per thread.
__global__ __launch_bounds__(192) void k_ln(const float* __restrict__ Hin,
                                            const float* __restrict__ gamma,
                                            const float* __restrict__ beta,
                                            const float* __restrict__ W2,
                                            const float* __restrict__ b2,
                                            const float* __restrict__ base,
                                            float* __restrict__ out) {
  __shared__ float redS[3], redQ[3], redp[3][LOUT];
  int row = blockIdx.x;
  int t = threadIdx.x;
  int lane = t & 63, wave = t >> 6;
  const float4 v = *(const float4*)(Hin + row * HDIM + t * 4);
  float s1 = v.x + v.y + v.z + v.w;
  float s2 = v.x*v.x + v.y*v.y + v.z*v.z + v.w*v.w;
  #pragma unroll
  for (int m = 1; m < 64; m <<= 1) { s1 += __shfl_xor(s1, m); s2 += __shfl_xor(s2, m); }
  if (lane == 0) { redS[wave] = s1; redQ[wave] = s2; }
  __syncthreads();
  s1 = redS[0] + redS[1] + redS[2];
  s2 = redQ[0] + redQ[1] + redQ[2];
  float mu = s1 * (1.f / HDIM);
  float var = s2 * (1.f / HDIM) - mu * mu;
  float rstd = rsqrtf(var + 1e-5f);
  const float4 g4 = *(const float4*)(gamma + t * 4);
  const float4 be4 = *(const float4*)(beta + t * 4);
  float p[LOUT] = {};
  const float vv[4] = { v.x, v.y, v.z, v.w };
  const float gv[4] = { g4.x, g4.y, g4.z, g4.w };
  const float bv[4] = { be4.x, be4.y, be4.z, be4.w };
  #pragma unroll
  for (int j = 0; j < 4; ++j) {
    float g = (vv[j] - mu) * rstd * gv[j] + bv[j];
    float gg = 0.5f * g * (1.f + erff(g * 0.70710678118654752f));
    const float* wrow = W2 + (t * 4 + j) * LOUT;
    #pragma unroll
    for (int l = 0; l < LOUT; ++l) p[l] += gg * wrow[l];
  }
  #pragma unroll
  for (int l = 0; l < LOUT; ++l)
    #pragma unroll
    for (int m = 1; m < 64; m <<= 1) p[l] += __shfl_xor(p[l], m);
  if (lane == 0) {
    #pragma unroll
    for (int l = 0; l < LOUT; ++l) redp[wave][l] = p[l];
  }
  __syncthreads();
  if (t < LOUT) {
    float cl = redp[0][t] + redp[1][t] + redp[2][t] + b2[t];
    out[row * LOUT + t] = 0.5f * base[row * LOUT + t] + 0.5f * cl;
  }
}

extern "C" void kernel_launch(void* const* d_in, const int* in_sizes, int n_in,
                              void* d_out, int out_size, void* d_ws, size_t ws_size,
                              hipStream_t stream) {
  const float* x     = (const float*)d_in[0];
  const float* Wc    = (const float*)d_in[1];
  const float* bc    = (const float*)d_in[2];
  const float* wa    = (const float*)d_in[3];
  const float* ba    = (const float*)d_in[4];
  const float* W1    = (const float*)d_in[5];
  const float* b1    = (const float*)d_in[6];
  const float* gamma = (const float*)d_in[7];
  const float* beta  = (const float*)d_in[8];
  const float* W2    = (const float*)d_in[9];
  const float* b2    = (const float*)d_in[10];
  float* out = (float*)d_out;

  char* ws = (char*)d_ws;
  unsigned short* xc  = (unsigned short*)(ws);             // 8192*1536*2  = 25,165,824
  unsigned short* w1t = (unsigned short*)(ws + 25165824);  // 768*1536*2   =  2,359,296
  float* scores       = (float*)(ws + 27525120);           // 8192*4       =     32,768
  float* base         = (float*)(ws + 27557888);           // 8192*9*4     =    294,912
  float* hbuf         = (float*)(ws + 27852800);           // 8192*768*4   = 25,165,824

  k_prep_w1t<<<dim3(1152), dim3(256), 0, stream>>>(W1, w1t);
  k_prep    <<<dim3(8192), dim3(192), 0, stream>>>(x, wa, ba, Wc, bc, xc, scores, base);
  k_ctx     <<<dim3(8192), dim3(192), 0, stream>>>(scores, xc);
  k_gemm    <<<dim3(768),  dim3(256), 0, stream>>>(xc, w1t, b1, hbuf);
  k_ln      <<<dim3(8192), dim3(192), 0, stream>>>(hbuf, gamma, beta, W2, b2, base, out);
}